// Round 2
// baseline (446.160 us; speedup 1.0000x reference)
//
#include <hip/hip_runtime.h>

// LGA3D x3 (GANet local guided aggregation), fp32.
// Round 2: 4 channels interleaved per LDS cell -> tap reads are ds_read_b128
// (4x fewer LDS instrs, ~2x effective LDS BW). Filters pinned in VGPRs via asm.

namespace {
constexpr int C  = 16, D = 48, H = 128, W = 256;
constexpr int NC = 4;                 // channels per thread (interleaved in LDS cells)
constexpr int TH = 4, TW = 32;        // output tile per block
constexpr int LH = TH + 4;            // 8 rows: h0-2 .. h0+TH+1
constexpr int LW = TW + 8;            // 40 cols: w0-4 .. w0+35 (covers w0-2..w0+33 taps)
constexpr int HW = H * W;
constexpr int DHW = D * HW;
constexpr int NF = 75;
constexpr int CELLS = LH * LW;        // 320 LDS cells per buffer (each = float4 of 4 c's)
}

__global__ __launch_bounds__(128, 2)
void lga_pass(const float* __restrict__ in, const float* __restrict__ filt,
              float* __restrict__ out)
{
    __shared__ float4 buf[2][CELLS];  // 2 x 5120 B

    const int tx  = threadIdx.x;      // 0..31
    const int ty  = threadIdx.y;      // 0..3
    const int tid = ty * 32 + tx;
    const int w0  = blockIdx.x * TW;
    const int h0  = blockIdx.y * TH;
    const int c0  = blockIdx.z * NC;
    const int h   = h0 + ty;
    const int w   = w0 + tx;

    // ---- filters -> VGPRs, reused for all 48 planes x 4 channels ----
    float f[NF];
    #pragma unroll
    for (int k = 0; k < NF; ++k)
        f[k] = filt[k * HW + h * W + w];
    // pin them: forbid the compiler from sinking these loads into the d-loop
    #pragma unroll
    for (int k = 0; k < NF; ++k)
        asm volatile("" : "+v"(f[k]));

    // ---- staging: each thread owns up to 3 cells (CELLS=320, 128 threads) ----
    // cell (r, col): r = LDS row (global h0-2+r), col = LDS col (global w0-4+col)
    const float* base = in + (size_t)c0 * DHW;

    auto stage = [&](int p, int bsel) {   // p = input plane 0..D-1
        #pragma unroll
        for (int k = 0; k < 3; ++k) {
            int cell = tid + k * 128;
            if (cell < CELLS) {
                int r   = cell / LW;
                int col = cell - r * LW;
                int gh  = h0 - 2 + r;
                int gw  = w0 - 4 + col;
                float4 v = make_float4(0.f, 0.f, 0.f, 0.f);
                if (gh >= 0 && gh < H && gw >= 0 && gw < W) {
                    const float* pb = base + (size_t)p * HW + gh * W + gw;
                    v.x = pb[0];
                    v.y = pb[DHW];
                    v.z = pb[2 * DHW];
                    v.w = pb[3 * DHW];
                }
                buf[bsel][cell] = v;
            }
        }
    };

    stage(0, 0);
    __syncthreads();

    // rolling accumulators (per channel): a_prev = partial out[d-1], a_cur = partial out[d]
    float4 a_prev = make_float4(0.f, 0.f, 0.f, 0.f);
    float4 a_cur  = make_float4(0.f, 0.f, 0.f, 0.f);
    float* op0 = out + (size_t)c0 * DHW + h * W + w;

    for (int d = 0; d < D; ++d) {
        if (d + 1 < D) stage(d + 1, (d + 1) & 1);

        // tap base: LDS row ty+i (global h-2+i), col tx+2+j (global w-2+j)
        const float4* bp = &buf[d & 1][ty * LW + tx + 2];
        float4 s0 = make_float4(0.f, 0.f, 0.f, 0.f);
        float4 s1 = s0, s2 = s0;
        #pragma unroll
        for (int i = 0; i < 5; ++i) {
            #pragma unroll
            for (int j = 0; j < 5; ++j) {
                float4 v = bp[i * LW + j];        // ds_read_b128: 4 channels at once
                float F0 = f[     i * 5 + j];
                float F1 = f[25 + i * 5 + j];
                float F2 = f[50 + i * 5 + j];
                s0.x = fmaf(F0, v.x, s0.x); s0.y = fmaf(F0, v.y, s0.y);
                s0.z = fmaf(F0, v.z, s0.z); s0.w = fmaf(F0, v.w, s0.w);
                s1.x = fmaf(F1, v.x, s1.x); s1.y = fmaf(F1, v.y, s1.y);
                s1.z = fmaf(F1, v.z, s1.z); s1.w = fmaf(F1, v.w, s1.w);
                s2.x = fmaf(F2, v.x, s2.x); s2.y = fmaf(F2, v.y, s2.y);
                s2.z = fmaf(F2, v.z, s2.z); s2.w = fmaf(F2, v.w, s2.w);
            }
        }

        if (d > 0) {   // out[d-1] complete: a_prev + s2(plane d)
            float* op = op0 + (size_t)(d - 1) * HW;
            op[0]       = a_prev.x + s2.x;
            op[DHW]     = a_prev.y + s2.y;
            op[2 * DHW] = a_prev.z + s2.z;
            op[3 * DHW] = a_prev.w + s2.w;
        }
        a_prev.x = a_cur.x + s1.x; a_prev.y = a_cur.y + s1.y;
        a_prev.z = a_cur.z + s1.z; a_prev.w = a_cur.w + s1.w;
        a_cur = s0;
        __syncthreads();   // generations are 2 apart; write-buf != any read-buf in flight
    }
    {   // out[D-1] = s0(D-2) + s1(D-1); s2 of plane D is zero
        float* op = op0 + (size_t)(D - 1) * HW;
        op[0]       = a_prev.x;
        op[DHW]     = a_prev.y;
        op[2 * DHW] = a_prev.z;
        op[3 * DHW] = a_prev.w;
    }
}

extern "C" void kernel_launch(void* const* d_in, const int* in_sizes, int n_in,
                              void* d_out, int out_size, void* d_ws, size_t ws_size,
                              hipStream_t stream)
{
    (void)in_sizes; (void)n_in; (void)out_size;
    const float* cost = (const float*)d_in[0];
    const float* filt = (const float*)d_in[1];
    float* out = (float*)d_out;

    const size_t needBytes = (size_t)C * DHW * sizeof(float);
    float* tmp = (ws_size >= needBytes) ? (float*)d_ws : (float*)d_in[0];
    // fallback writes the input buffer; harness restores d_in before every timed launch

    dim3 block(32, 4, 1);
    dim3 grid(W / TW, H / TH, C / NC);   // 8 x 32 x 4 = 1024 blocks

    lga_pass<<<grid, block, 0, stream>>>(cost, filt, out);   // pass 1: cost -> out
    lga_pass<<<grid, block, 0, stream>>>(out,  filt, tmp);   // pass 2: out  -> tmp
    lga_pass<<<grid, block, 0, stream>>>(tmp,  filt, out);   // pass 3: tmp  -> out
}